// Round 6
// baseline (1300.107 us; speedup 1.0000x reference)
//
#include <hip/hip_runtime.h>

typedef unsigned short u16;
typedef unsigned int   u32;
typedef short bf16x8 __attribute__((ext_vector_type(8)));
typedef float f32x4  __attribute__((ext_vector_type(4)));

// ---------- geometry ----------
#define Bn   2
#define Nn   7
#define Cc   128
#define Hh   120
#define Ww   360
#define HW   43200          // Hh*Ww
#define PIX  86400          // Bn*HW
#define HP   122            // padded H (h index +1)
#define WP   362            // padded W (w index +1)
#define ICP1 928            // 29*32 (898 real + pad)
#define ICP2 192            // 6*32  (176 real + pad)

// ---------- ws layout (bytes, 256-aligned) ----------
constexpr size_t AL(size_t x){ return (x + 255) & ~size_t(255); }
constexpr size_t XH_BYTES  = (size_t)Bn*HP*WP*ICP1*2;      // ~163.9 MB
constexpr size_t LRS_BYTES = (size_t)Bn*HP*WP*ICP2*2;      // ~33.9 MB
constexpr size_t OFF_XH  = 0;
constexpr size_t OFF_LRS = AL(OFF_XH + XH_BYTES + 65536);     // slack for conv A-tile overrun
constexpr size_t OFF_FEAT= AL(OFF_LRS + LRS_BYTES + 65536);   // feat aliases mh (mh dead before conv)
constexpr size_t OFF_W1F = AL(OFF_FEAT + (size_t)PIX*128*2);
constexpr size_t OFF_W2F = AL(OFF_W1F + (size_t)9*30*128*32*2);   // 30 chunks (29 real + zero pad)
constexpr size_t OFF_W2B = AL(OFF_W2F + (size_t)9*6*64*32*2);
constexpr size_t OFF_CN  = AL(OFF_W2B + 256);
constexpr size_t OFF_GST = AL(OFF_CN + (size_t)PIX*4);
// offsets buffer (f32, PIX*64*4 = 22.1MB) aliases xh (xh dead after main conv)

// ---------- helpers ----------
__device__ __forceinline__ float bf2f(u16 h){ union{u32 u; float f;} c; c.u = ((u32)h)<<16; return c.f; }
__device__ __forceinline__ u16 f2bf(float f){
  union{float f; u32 u;} c; c.f = f;
  u32 r = (c.u + 0x7FFFu + ((c.u>>16)&1u)) >> 16;
  return (u16)r;
}
__device__ __forceinline__ float bflo(u32 a){ union{u32 u; float f;} c; c.u = a<<16;          return c.f; }
__device__ __forceinline__ float bfhi(u32 a){ union{u32 u; float f;} c; c.u = a & 0xffff0000u; return c.f; }

__device__ __forceinline__ void gl_lds16(const u16* g, u16* l){
  __builtin_amdgcn_global_load_lds((const __attribute__((address_space(1))) void*)g,
                                   (__attribute__((address_space(3))) void*)l, 16, 0, 0);
}

// ---------- init: zero gstats + spatial pads of xh / lrs ----------
__global__ __launch_bounds__(256) void k_init(u16* __restrict__ xh, u16* __restrict__ lrs, float* __restrict__ gstats)
{
  int t = blockIdx.x*256 + threadIdx.x;
  if (t < 64) gstats[t] = 0.f;
  t -= 64;
  if (t < 0 || t >= 2*964*140) return;
  int b = t / (964*140); int r = t - b*(964*140);
  int i = r / 140, chunk = r - i*140;
  int hp, wp;
  if (i < 362)      { hp = 0;   wp = i; }
  else if (i < 724) { hp = 121; wp = i-362; }
  else { int j = i-724; hp = 1 + (j>>1); wp = (j&1) ? 361 : 0; }
  size_t pixel = (size_t)(b*HP + hp)*WP + wp;
  uint4 z = make_uint4(0,0,0,0);
  if (chunk < 116) ((uint4*)(xh  + pixel*ICP1))[chunk]      = z;
  else             ((uint4*)(lrs + pixel*ICP2))[chunk-116]  = z;
}

// ---------- weight prep: MFMA-fragment-ordered  [tap][chunk(30)][oc][32] ----------
__global__ __launch_bounds__(256) void k_prep_w1(const float* __restrict__ cw, u16* __restrict__ w1f)
{
  int t = blockIdx.x*256 + threadIdx.x;      // 9*30*128*32
  int kk = t & 31; int rest = t >> 5;
  int oc = rest & 127; rest >>= 7;           // rest = tap*30 + c
  int c = rest % 30, tap = rest / 30;
  int ic = c*32 + kk;
  u16 v = 0;
  if (ic < 898) v = f2bf(cw[(size_t)oc*8082 + (size_t)ic*9 + tap]);
  w1f[t] = v;
}

__global__ __launch_bounds__(256) void k_prep_w2(const float* __restrict__ ow0, const float* __restrict__ ow1,
    const float* __restrict__ ow2, const float* __restrict__ ob0, const float* __restrict__ ob1,
    const float* __restrict__ ob2, u16* __restrict__ w2f, float* __restrict__ w2b)
{
  int t = blockIdx.x*256 + threadIdx.x;      // 9*6*64*32
  if (t < 64) {
    float bv = 0.f;
    if (t < 32)      bv = ob0[t];
    else if (t < 48) bv = ob1[t-32];
    else if (t < 56) bv = ob2[t-48];
    w2b[t] = bv;
  }
  int kk = t & 31; int rest = t >> 5;
  int oc = rest & 63; rest >>= 6;            // rest = tap*6 + c
  int c = rest % 6, tap = rest / 6;
  int ic = c*32 + kk;
  u16 v = 0;
  if (ic < 176) {
    if (oc < 32)      v = f2bf(ow0[(size_t)oc*1584      + (size_t)ic*9 + tap]);
    else if (oc < 48) v = f2bf(ow1[(size_t)(oc-32)*1584 + (size_t)ic*9 + tap]);
    else if (oc < 56) v = f2bf(ow2[(size_t)(oc-48)*1584 + (size_t)ic*9 + tap]);
  }
  w2f[t] = v;
}

// ---------- fused pack + mean + GN stats, v2 ----------
__global__ __launch_bounds__(256) void k_packmean(const float* __restrict__ x, u16* __restrict__ xh,
                                                  u16* __restrict__ mh, float* __restrict__ gstats)
{
  int wt = blockIdx.x, h = blockIdx.y, b = blockIdx.z;
  int t = threadIdx.x;
  int wg = t & 15, cq = t >> 4;
  int w0 = wt*64 + wg*4;
  bool ok = (w0 < Ww);                 // 4-pixel group all-valid or all-invalid
  int w0c = ok ? w0 : 0;
  const float* xb = x + (size_t)b*7*128*HW + (size_t)h*Ww + w0c;
  u16* recbase = xh + ((size_t)(b*HP + h+1)*WP + (w0c+1))*ICP1;

  float msum[8][4];
  #pragma unroll
  for (int c = 0; c < 8; ++c)
    #pragma unroll
    for (int s = 0; s < 4; ++s) msum[c][s] = 0.f;

  #pragma unroll
  for (int nn = 0; nn < 7; ++nn) {
    float4 v[8];
    const float* src = xb + (size_t)(nn*128 + cq*8)*HW;
    #pragma unroll
    for (int c = 0; c < 8; ++c)
      v[c] = ok ? *(const float4*)(src + (size_t)c*HW) : make_float4(0.f,0.f,0.f,0.f);
    #pragma unroll
    for (int c = 0; c < 8; ++c) {
      const float* vf = (const float*)&v[c];
      #pragma unroll
      for (int s = 0; s < 4; ++s) msum[c][s] += vf[s];
    }
    if (ok) {
      #pragma unroll
      for (int s = 0; s < 4; ++s) {
        u32 ow[4];
        #pragma unroll
        for (int e = 0; e < 4; ++e) {
          const float* lo = (const float*)&v[2*e];
          const float* hi = (const float*)&v[2*e+1];
          ow[e] = (u32)f2bf(lo[s]) | ((u32)f2bf(hi[s]) << 16);
        }
        *(uint4*)(recbase + (size_t)s*ICP1 + nn*128 + cq*8) = make_uint4(ow[0],ow[1],ow[2],ow[3]);
      }
    }
  }
  // mean -> mh, GN partials
  float g1 = 0.f, g2 = 0.f;
  #pragma unroll
  for (int c = 0; c < 8; ++c)
    #pragma unroll
    for (int s = 0; s < 4; ++s) {
      float m = msum[c][s] * (1.f/7.f);
      msum[c][s] = m;
      g1 += m; g2 += m*m;
    }
  if (ok) {
    #pragma unroll
    for (int s = 0; s < 4; ++s) {
      u32 ow[4];
      #pragma unroll
      for (int e = 0; e < 4; ++e)
        ow[e] = (u32)f2bf(msum[2*e][s]) | ((u32)f2bf(msum[2*e+1][s]) << 16);
      *(uint4*)(mh + ((size_t)b*HW + (size_t)h*Ww + w0 + s)*128 + cq*8) = make_uint4(ow[0],ow[1],ow[2],ow[3]);
    }
  }
  #pragma unroll
  for (int o = 8; o > 0; o >>= 1) { g1 += __shfl_down(g1, o, 16); g2 += __shfl_down(g2, o, 16); }
  if (wg == 0) {
    int gi = (b*16 + cq)*2;
    atomicAdd(&gstats[gi],   g1);
    atomicAdd(&gstats[gi+1], g2);
  }
  // coords + zero pad (chunk 28): wave 0, one record per lane
  if (t < 64) {
    int w = wt*64 + t;
    if (w < Ww) {
      u16* rc = xh + ((size_t)(b*HP + h+1)*WP + (w+1))*ICP1 + 896;
      u32 cw0 = (u32)f2bf((float)w*(2.f/359.f) - 1.f) | ((u32)f2bf((float)h*(2.f/119.f) - 1.f) << 16);
      ((uint4*)rc)[0] = make_uint4(cw0, 0, 0, 0);
      ((uint4*)rc)[1] = make_uint4(0,0,0,0);
      ((uint4*)rc)[2] = make_uint4(0,0,0,0);
      ((uint4*)rc)[3] = make_uint4(0,0,0,0);
    }
  }
}

// ---------- pass A: group-norm -> lr into lrs[ch 0..128), zeros 176..192), per-pixel norm ----------
__global__ __launch_bounds__(256) void k_passA(const u16* __restrict__ mh, const float* __restrict__ gg,
    const float* __restrict__ gb, const float* __restrict__ gstats, u16* __restrict__ lrs, float* __restrict__ cn)
{
  __shared__ float sg[128], sb[128], smu[32], srs[32];
  int tid = threadIdx.x;
  if (tid < 128){ sg[tid] = gg[tid]; sb[tid] = gb[tid]; }
  else if (tid < 160){
    int i = tid-128;
    float s = gstats[2*i], s2 = gstats[2*i+1];
    float mu = s * (1.f/345600.f);
    float var = s2 * (1.f/345600.f) - mu*mu; if (var < 0.f) var = 0.f;
    smu[i] = mu; srs[i] = rsqrtf(var + 1e-5f);
  }
  __syncthreads();
  int p = blockIdx.x*256 + tid; if (p >= PIX) return;
  int b = p / HW, pix = p - b*HW, h = pix/Ww, w = pix - h*Ww;
  const uint4* src = (const uint4*)(mh + (size_t)p*128);
  u16* dst = lrs + ((size_t)(b*HP + h+1)*WP + (w+1))*ICP2;
  float ss = 0.f;
  #pragma unroll
  for (int t = 0; t < 16; ++t) {
    uint4 v = src[t];
    u32 wds[4] = {v.x, v.y, v.z, v.w};
    u32 ot[4];
    #pragma unroll
    for (int e = 0; e < 4; ++e) {
      int c0 = t*8 + e*2;
      int g0 = b*16 + (c0>>3);
      float a0 = (bflo(wds[e]) - smu[g0])*srs[g0]*sg[c0]   + sb[c0];
      float a1 = (bfhi(wds[e]) - smu[g0])*srs[g0]*sg[c0+1] + sb[c0+1];
      ss += a0*a0 + a1*a1;
      ot[e] = (u32)f2bf(a0) | ((u32)f2bf(a1) << 16);
    }
    ((uint4*)dst)[t] = make_uint4(ot[0], ot[1], ot[2], ot[3]);
  }
  uint4 z = make_uint4(0,0,0,0);
  ((uint4*)dst)[22] = z; ((uint4*)dst)[23] = z;      // channels 176..191
  cn[p] = fmaxf(sqrtf(ss), 1e-8f);
}

// ---------- pass B: 48 dilated cosine sims into lrs[ch 128..176) ----------
__global__ __launch_bounds__(256) void k_passB(u16* __restrict__ lrs, const float* __restrict__ cn)
{
  int p = blockIdx.x*256 + threadIdx.x; if (p >= PIX) return;
  int b = p / HW, pix = p - b*HW, h = pix/Ww, w = pix - h*Ww;
  u16* base = lrs + ((size_t)(b*HP + h+1)*WP + (w+1))*ICP2;
  uint4 own[16];
  #pragma unroll
  for (int t = 0; t < 16; ++t) own[t] = ((const uint4*)base)[t];
  float cnp = cn[p];
  u32 outw[24] __attribute__((aligned(16)));
  int k = 0;
  for (int i = 0; i < 7; ++i)
    for (int j = 0; j < 7; ++j) {
      if (i == 3 && j == 3) continue;
      int hq = h + 2*i - 6, wq = w + 2*j - 6;
      float sim = 0.f;
      if ((unsigned)hq < 120u && (unsigned)wq < 360u) {
        const u16* nb = lrs + ((size_t)(b*HP + hq+1)*WP + (wq+1))*ICP2;
        float dot = 0.f;
        #pragma unroll
        for (int t = 0; t < 16; ++t) {
          uint4 a = own[t]; uint4 c = ((const uint4*)nb)[t];
          dot += bflo(a.x)*bflo(c.x) + bfhi(a.x)*bfhi(c.x);
          dot += bflo(a.y)*bflo(c.y) + bfhi(a.y)*bfhi(c.y);
          dot += bflo(a.z)*bflo(c.z) + bfhi(a.z)*bfhi(c.z);
          dot += bflo(a.w)*bflo(c.w) + bfhi(a.w)*bfhi(c.w);
        }
        sim = dot / (cnp * cn[b*HW + hq*Ww + wq]);
      }
      u32 bv = f2bf(sim);
      if (k & 1) outw[k>>1] |= bv << 16; else outw[k>>1] = bv;
      ++k;
    }
  #pragma unroll
  for (int t = 0; t < 6; ++t) ((uint4*)(base + 128))[t] = ((uint4*)outw)[t];
}

// ---------- implicit-GEMM 3x3 conv, bf16 MFMA 16x16x32, BK=64 staging ----------
// v5: retile 2hx64w -> 2hx32w. Grid 720 -> 1440 blocks (5.6/CU); LDS buffer
// 33.8 -> 17.4 KB, dbuf 34.8 KB -> 4 blocks/CU resident = 4 waves/SIMD
// (double the latency hiding; v4's measured 18% occupancy was grid-capped at
// 2.8 blocks/CU). acc halves to 32 VGPR (4 M-frags: WM=2 at NWM=2).
// Inner pipeline identical to v4: b0/b1 named-register B-prefetch ping-pong,
// LOADB issued BEFORE STAGE so B-waits don't drain the stage (vmcnt FIFO).
template<int NSUPER, int NCTOT, int ICPAD, int OC, int NWM, int NWN, bool RELU, bool OUTF32>
__global__ __launch_bounds__(256, 4) void k_conv(const u16* __restrict__ inb, const u16* __restrict__ wf,
                                                 const float* __restrict__ bias, void* __restrict__ outp)
{
  static_assert(NWM*NWN == 4, "4 waves");
  constexpr int WM = 4/NWM;                 // of 4 M-frags (2h x 2 w-halves)
  constexpr int WN = (OC/16)/NWN;
  __shared__ __align__(16) u16 alds0[4*34*64];     // 17,408 B each
  __shared__ __align__(16) u16 alds1[4*34*64];
  const int wt = blockIdx.x, h2 = blockIdx.y, b = blockIdx.z;
  const int h0 = h2*2, w0 = wt*32;
  const int tid = threadIdx.x, wid = tid >> 6, lane = tid & 63;
  const int q = lane >> 4, n = lane & 15;
  const int mi = wid / NWN, ni = wid % NWN;

  f32x4 zz = {0.f,0.f,0.f,0.f};
  f32x4 acc[WM][WN];
  #pragma unroll
  for (int a = 0; a < WM; ++a)
    #pragma unroll
    for (int bq = 0; bq < WN; ++bq) acc[a][bq] = zz;

  bf16x8 b0[WN], b1[WN];                   // depth-2 B prefetch ring (named)

  const size_t pixbase = (size_t)(b*HP + h0)*WP + w0;
  const u16* wbase = wf + ((size_t)(ni*WN)*16 + n)*32 + q*8;   // oc-gn stride 16*32

  // wave `wid` stages input row wid: 34 wc x 8 units of 16B, XOR-swizzled
  // (pre-swizzled GLOBAL source, linear LDS dest -- gl_lds requirement)
  auto STAGE = [&](u16* dst, int C){
    const int row = wid;
    const u16* gbase = inb + (pixbase + (size_t)row*WP)*ICPAD + C*64;
    #pragma unroll
    for (int o = 0; o < 5; ++o) {
      if (o < 4 || lane < 16) {
        int f = o*64 + lane;                  // 0..271
        int wc = f >> 3, us = f & 7;
        int ridx = row*34 + wc;
        int usrc = us ^ (ridx & 7);
        gl_lds16(gbase + (size_t)wc*ICPAD + usrc*8, dst + (row*272 + o*64)*8);
      }
    }
  };

  // load B set for flat subtile f = s*9+tap of superchunk C into bb[]
  auto LOADB = [&](bf16x8 (&bb)[WN], int C, int f){
    const int s = f/9, tap = f%9;
    #pragma unroll
    for (int gn = 0; gn < WN; ++gn)
      bb[gn] = *(const bf16x8*)(wbase + (((size_t)tap*NCTOT + C*2+s)*OC + gn*16)*32);
  };

  // compute flat subtile f with B fragments bb[]
  auto CSUB = [&](const u16* buf, int f, const bf16x8 (&bb)[WN]){
    const int s = f/9, tap = f%9;
    const int kh = tap/3, kw = tap%3;
    bf16x8 afr[WM];
    #pragma unroll
    for (int gm = 0; gm < WM; ++gm) {
      int G = mi*WM + gm;                    // G: bit1 = h-row, bit0 = w-half
      int idx = ((G>>1) + kh)*34 + (G&1)*16 + n + kw;
      int us = (s*4 + q) ^ (idx & 7);
      afr[gm] = *(const bf16x8*)(buf + (idx*8 + us)*8);
    }
    #pragma unroll
    for (int gm = 0; gm < WM; ++gm)
      #pragma unroll
      for (int gn = 0; gn < WN; ++gn)
        acc[gm][gn] = __builtin_amdgcn_mfma_f32_16x16x32_bf16(afr[gm], bb[gn], acc[gm][gn], 0, 0, 0);
  };

  // PHASE(C): prefetch 2 B-sets, issue stage, then 18 subtiles ping-pong
  auto PHASE = [&](const u16* cur, u16* nxt, int C){
    LOADB(b0, C, 0);
    LOADB(b1, C, 1);
    if (C + 1 < NSUPER) STAGE(nxt, C + 1);
    #pragma unroll
    for (int ff = 0; ff < 9; ++ff) {
      CSUB(cur, 2*ff, b0);
      if (2*ff + 2 < 18) LOADB(b0, C, 2*ff + 2);
      CSUB(cur, 2*ff + 1, b1);
      if (2*ff + 3 < 18) LOADB(b1, C, 2*ff + 3);
    }
    __syncthreads();
  };

  STAGE(alds0, 0);
  __syncthreads();
  for (int CC = 0; CC < NSUPER; CC += 2) {
    PHASE(alds0, alds1, CC);
    if (CC + 1 < NSUPER) PHASE(alds1, alds0, CC + 1);
  }

  #pragma unroll
  for (int gn = 0; gn < WN; ++gn) {
    int oc = (ni*WN + gn)*16 + n;
    float bv = bias[oc];
    #pragma unroll
    for (int gm = 0; gm < WM; ++gm) {
      int G = mi*WM + gm;
      int h = h0 + (G>>1);
      #pragma unroll
      for (int r = 0; r < 4; ++r) {
        int m = q*4 + r;                      // pixel-within-16 (w offset)
        int w = w0 + (G&1)*16 + m;
        if (w < Ww) {
          float v = acc[gm][gn][r] + bv;
          if (RELU) v = fmaxf(v, 0.f);
          size_t oi = ((size_t)(b*Hh + h)*Ww + w)*OC + oc;
          if (OUTF32) ((float*)outp)[oi] = v;
          else        ((u16*)outp)[oi]  = f2bf(v);
        }
      }
    }
  }
}

// ---------- deform-sample 3 offset sets + average, NCHW f32 out ----------
__device__ __forceinline__ void samp_add(float* acc, const u16* __restrict__ feat,
                                         int b, int h, int w, float ox, float oy, int c0)
{
  float ix = (float)w + ox, iy = (float)h + oy;
  float x0f = floorf(ix), y0f = floorf(iy);
  float wx = ix - x0f, wy = iy - y0f;
  int x0 = (int)x0f, y0 = (int)y0f;
  int x0c = min(max(x0, 0), 359),   x1c = min(max(x0+1, 0), 359);
  int y0c = min(max(y0, 0), 119),   y1c = min(max(y0+1, 0), 119);
  const u16* fb = feat + (size_t)b*HW*128 + c0;
  uint4 v00 = *(const uint4*)(fb + ((size_t)y0c*Ww + x0c)*128);
  uint4 v01 = *(const uint4*)(fb + ((size_t)y0c*Ww + x1c)*128);
  uint4 v10 = *(const uint4*)(fb + ((size_t)y1c*Ww + x0c)*128);
  uint4 v11 = *(const uint4*)(fb + ((size_t)y1c*Ww + x1c)*128);
  float w00 = (1.f-wx)*(1.f-wy), w01 = wx*(1.f-wy), w10 = (1.f-wx)*wy, w11 = wx*wy;
  u32 a00[4] = {v00.x,v00.y,v00.z,v00.w};
  u32 a01[4] = {v01.x,v01.y,v01.z,v01.w};
  u32 a10[4] = {v10.x,v10.y,v10.z,v10.w};
  u32 a11[4] = {v11.x,v11.y,v11.z,v11.w};
  #pragma unroll
  for (int e = 0; e < 4; ++e) {
    acc[2*e]   += w00*bflo(a00[e]) + w01*bflo(a01[e]) + w10*bflo(a10[e]) + w11*bflo(a11[e]);
    acc[2*e+1] += w00*bfhi(a00[e]) + w01*bfhi(a01[e]) + w10*bfhi(a10[e]) + w11*bfhi(a11[e]);
  }
}

__global__ __launch_bounds__(256) void k_sample(const u16* __restrict__ feat, const float* __restrict__ offs,
                                                float* __restrict__ out)
{
  int lane = threadIdx.x & 63;
  int cc = blockIdx.y*4 + (threadIdx.x >> 6);     // 0..15: 8-channel chunk
  int pix = blockIdx.x*64 + lane;                 // 675*64 = 43200 exact
  int b = blockIdx.z;
  int h = pix/Ww, w = pix - h*Ww;
  const float* ob = offs + ((size_t)b*HW + pix)*64;
  float acc[8] = {0,0,0,0,0,0,0,0};
  samp_add(acc, feat, b, h, w, ob[cc],          ob[16+cc],       cc*8);   // off0: 16 groups
  samp_add(acc, feat, b, h, w, ob[32+(cc>>1)],  ob[40+(cc>>1)],  cc*8);   // off1: 8 groups
  samp_add(acc, feat, b, h, w, ob[48+(cc>>2)],  ob[52+(cc>>2)],  cc*8);   // off2: 4 groups
  #pragma unroll
  for (int e = 0; e < 8; ++e)
    out[((size_t)(b*128 + cc*8 + e))*HW + pix] = acc[e] * (1.f/3.f);
}

// ---------- launch ----------
extern "C" void kernel_launch(void* const* d_in, const int* in_sizes, int n_in,
                              void* d_out, int out_size, void* d_ws, size_t ws_size,
                              hipStream_t stream)
{
  (void)in_sizes; (void)n_in; (void)out_size; (void)ws_size;
  const float* x      = (const float*)d_in[0];
  const float* conv_w = (const float*)d_in[1];
  const float* conv_b = (const float*)d_in[2];
  const float* gn_g   = (const float*)d_in[3];
  const float* gn_b   = (const float*)d_in[4];
  const float* off_w  = (const float*)d_in[5];
  const float* off_b  = (const float*)d_in[6];
  const float* off1_w = (const float*)d_in[7];
  const float* off1_b = (const float*)d_in[8];
  const float* off2_w = (const float*)d_in[9];
  const float* off2_b = (const float*)d_in[10];
  float* out = (float*)d_out;

  char* ws = (char*)d_ws;
  u16*   xh   = (u16*)(ws + OFF_XH);
  u16*   lrs  = (u16*)(ws + OFF_LRS);
  u16*   mh   = (u16*)(ws + OFF_FEAT);   // aliases feat (mh consumed in passA before conv writes feat)
  u16*   feat = mh;
  float* offs = (float*)(ws + OFF_XH);   // aliases xh (xh consumed by conv1 before conv2 writes offs)
  u16*   w1f  = (u16*)(ws + OFF_W1F);
  u16*   w2f  = (u16*)(ws + OFF_W2F);
  float* w2b  = (float*)(ws + OFF_W2B);
  float* cn   = (float*)(ws + OFF_CN);
  float* gst  = (float*)(ws + OFF_GST);

  k_init    <<<dim3(1055),      dim3(256), 0, stream>>>(xh, lrs, gst);
  k_prep_w1 <<<dim3(4320),      dim3(256), 0, stream>>>(conv_w, w1f);
  k_prep_w2 <<<dim3(432),       dim3(256), 0, stream>>>(off_w, off1_w, off2_w, off_b, off1_b, off2_b, w2f, w2b);
  k_packmean<<<dim3(6,120,2),   dim3(256), 0, stream>>>(x, xh, mh, gst);
  k_passA   <<<dim3(338),       dim3(256), 0, stream>>>(mh, gn_g, gn_b, gst, lrs, cn);
  k_passB   <<<dim3(338),       dim3(256), 0, stream>>>(lrs, cn);
  k_conv<15,30,ICP1,128,2,2,true ,false><<<dim3(12,60,2), dim3(256), 0, stream>>>(xh,  w1f, conv_b, feat);
  k_conv< 3, 6,ICP2, 64,2,2,false,true ><<<dim3(12,60,2), dim3(256), 0, stream>>>(lrs, w2f, w2b,   offs);
  k_sample  <<<dim3(675,4,2),   dim3(256), 0, stream>>>(feat, offs, out);
}

// Round 7
// 1226.109 us; speedup vs baseline: 1.0604x; 1.0604x over previous
//
#include <hip/hip_runtime.h>

typedef unsigned short u16;
typedef unsigned int   u32;
typedef short bf16x8 __attribute__((ext_vector_type(8)));
typedef float f32x4  __attribute__((ext_vector_type(4)));

// ---------- geometry ----------
#define Bn   2
#define Nn   7
#define Cc   128
#define Hh   120
#define Ww   360
#define HW   43200          // Hh*Ww
#define PIX  86400          // Bn*HW
#define HP   122            // padded H (h index +1)
#define WP   362            // padded W (w index +1)
#define ICP1 928            // 29*32 (898 real + pad)
#define ICP2 192            // 6*32  (176 real + pad)

// ---------- ws layout (bytes, 256-aligned) ----------
constexpr size_t AL(size_t x){ return (x + 255) & ~size_t(255); }
constexpr size_t XH_BYTES  = (size_t)Bn*HP*WP*ICP1*2;      // ~163.9 MB
constexpr size_t LRS_BYTES = (size_t)Bn*HP*WP*ICP2*2;      // ~33.9 MB
constexpr size_t OFF_XH  = 0;
constexpr size_t OFF_LRS = AL(OFF_XH + XH_BYTES + 65536);     // slack for conv A-tile overrun
constexpr size_t OFF_FEAT= AL(OFF_LRS + LRS_BYTES + 65536);   // feat aliases mh (mh dead before conv)
constexpr size_t OFF_W1F = AL(OFF_FEAT + (size_t)PIX*128*2);
constexpr size_t OFF_W2F = AL(OFF_W1F + (size_t)9*30*128*32*2);   // 30 chunks (29 real + zero pad)
constexpr size_t OFF_W2B = AL(OFF_W2F + (size_t)9*6*64*32*2);
constexpr size_t OFF_CN  = AL(OFF_W2B + 256);
constexpr size_t OFF_GST = AL(OFF_CN + (size_t)PIX*4);
// offsets buffer (f32, PIX*64*4 = 22.1MB) aliases xh (xh dead after main conv)

// ---------- helpers ----------
__device__ __forceinline__ float bf2f(u16 h){ union{u32 u; float f;} c; c.u = ((u32)h)<<16; return c.f; }
__device__ __forceinline__ u16 f2bf(float f){
  union{float f; u32 u;} c; c.f = f;
  u32 r = (c.u + 0x7FFFu + ((c.u>>16)&1u)) >> 16;
  return (u16)r;
}
__device__ __forceinline__ float bflo(u32 a){ union{u32 u; float f;} c; c.u = a<<16;          return c.f; }
__device__ __forceinline__ float bfhi(u32 a){ union{u32 u; float f;} c; c.u = a & 0xffff0000u; return c.f; }

__device__ __forceinline__ void gl_lds16(const u16* g, u16* l){
  __builtin_amdgcn_global_load_lds((const __attribute__((address_space(1))) void*)g,
                                   (__attribute__((address_space(3))) void*)l, 16, 0, 0);
}

// ---------- init: zero gstats + spatial pads of xh / lrs ----------
__global__ __launch_bounds__(256) void k_init(u16* __restrict__ xh, u16* __restrict__ lrs, float* __restrict__ gstats)
{
  int t = blockIdx.x*256 + threadIdx.x;
  if (t < 64) gstats[t] = 0.f;
  t -= 64;
  if (t < 0 || t >= 2*964*140) return;
  int b = t / (964*140); int r = t - b*(964*140);
  int i = r / 140, chunk = r - i*140;
  int hp, wp;
  if (i < 362)      { hp = 0;   wp = i; }
  else if (i < 724) { hp = 121; wp = i-362; }
  else { int j = i-724; hp = 1 + (j>>1); wp = (j&1) ? 361 : 0; }
  size_t pixel = (size_t)(b*HP + hp)*WP + wp;
  uint4 z = make_uint4(0,0,0,0);
  if (chunk < 116) ((uint4*)(xh  + pixel*ICP1))[chunk]      = z;
  else             ((uint4*)(lrs + pixel*ICP2))[chunk-116]  = z;
}

// ---------- weight prep: MFMA-fragment-ordered  [tap][chunk(30)][oc][32] ----------
__global__ __launch_bounds__(256) void k_prep_w1(const float* __restrict__ cw, u16* __restrict__ w1f)
{
  int t = blockIdx.x*256 + threadIdx.x;      // 9*30*128*32
  int kk = t & 31; int rest = t >> 5;
  int oc = rest & 127; rest >>= 7;           // rest = tap*30 + c
  int c = rest % 30, tap = rest / 30;
  int ic = c*32 + kk;
  u16 v = 0;
  if (ic < 898) v = f2bf(cw[(size_t)oc*8082 + (size_t)ic*9 + tap]);
  w1f[t] = v;
}

__global__ __launch_bounds__(256) void k_prep_w2(const float* __restrict__ ow0, const float* __restrict__ ow1,
    const float* __restrict__ ow2, const float* __restrict__ ob0, const float* __restrict__ ob1,
    const float* __restrict__ ob2, u16* __restrict__ w2f, float* __restrict__ w2b)
{
  int t = blockIdx.x*256 + threadIdx.x;      // 9*6*64*32
  if (t < 64) {
    float bv = 0.f;
    if (t < 32)      bv = ob0[t];
    else if (t < 48) bv = ob1[t-32];
    else if (t < 56) bv = ob2[t-48];
    w2b[t] = bv;
  }
  int kk = t & 31; int rest = t >> 5;
  int oc = rest & 63; rest >>= 6;            // rest = tap*6 + c
  int c = rest % 6, tap = rest / 6;
  int ic = c*32 + kk;
  u16 v = 0;
  if (ic < 176) {
    if (oc < 32)      v = f2bf(ow0[(size_t)oc*1584      + (size_t)ic*9 + tap]);
    else if (oc < 48) v = f2bf(ow1[(size_t)(oc-32)*1584 + (size_t)ic*9 + tap]);
    else if (oc < 56) v = f2bf(ow2[(size_t)(oc-48)*1584 + (size_t)ic*9 + tap]);
  }
  w2f[t] = v;
}

// ---------- fused pack + mean + GN stats, v2 ----------
__global__ __launch_bounds__(256) void k_packmean(const float* __restrict__ x, u16* __restrict__ xh,
                                                  u16* __restrict__ mh, float* __restrict__ gstats)
{
  int wt = blockIdx.x, h = blockIdx.y, b = blockIdx.z;
  int t = threadIdx.x;
  int wg = t & 15, cq = t >> 4;
  int w0 = wt*64 + wg*4;
  bool ok = (w0 < Ww);                 // 4-pixel group all-valid or all-invalid
  int w0c = ok ? w0 : 0;
  const float* xb = x + (size_t)b*7*128*HW + (size_t)h*Ww + w0c;
  u16* recbase = xh + ((size_t)(b*HP + h+1)*WP + (w0c+1))*ICP1;

  float msum[8][4];
  #pragma unroll
  for (int c = 0; c < 8; ++c)
    #pragma unroll
    for (int s = 0; s < 4; ++s) msum[c][s] = 0.f;

  #pragma unroll
  for (int nn = 0; nn < 7; ++nn) {
    float4 v[8];
    const float* src = xb + (size_t)(nn*128 + cq*8)*HW;
    #pragma unroll
    for (int c = 0; c < 8; ++c)
      v[c] = ok ? *(const float4*)(src + (size_t)c*HW) : make_float4(0.f,0.f,0.f,0.f);
    #pragma unroll
    for (int c = 0; c < 8; ++c) {
      const float* vf = (const float*)&v[c];
      #pragma unroll
      for (int s = 0; s < 4; ++s) msum[c][s] += vf[s];
    }
    if (ok) {
      #pragma unroll
      for (int s = 0; s < 4; ++s) {
        u32 ow[4];
        #pragma unroll
        for (int e = 0; e < 4; ++e) {
          const float* lo = (const float*)&v[2*e];
          const float* hi = (const float*)&v[2*e+1];
          ow[e] = (u32)f2bf(lo[s]) | ((u32)f2bf(hi[s]) << 16);
        }
        *(uint4*)(recbase + (size_t)s*ICP1 + nn*128 + cq*8) = make_uint4(ow[0],ow[1],ow[2],ow[3]);
      }
    }
  }
  // mean -> mh, GN partials
  float g1 = 0.f, g2 = 0.f;
  #pragma unroll
  for (int c = 0; c < 8; ++c)
    #pragma unroll
    for (int s = 0; s < 4; ++s) {
      float m = msum[c][s] * (1.f/7.f);
      msum[c][s] = m;
      g1 += m; g2 += m*m;
    }
  if (ok) {
    #pragma unroll
    for (int s = 0; s < 4; ++s) {
      u32 ow[4];
      #pragma unroll
      for (int e = 0; e < 4; ++e)
        ow[e] = (u32)f2bf(msum[2*e][s]) | ((u32)f2bf(msum[2*e+1][s]) << 16);
      *(uint4*)(mh + ((size_t)b*HW + (size_t)h*Ww + w0 + s)*128 + cq*8) = make_uint4(ow[0],ow[1],ow[2],ow[3]);
    }
  }
  #pragma unroll
  for (int o = 8; o > 0; o >>= 1) { g1 += __shfl_down(g1, o, 16); g2 += __shfl_down(g2, o, 16); }
  if (wg == 0) {
    int gi = (b*16 + cq)*2;
    atomicAdd(&gstats[gi],   g1);
    atomicAdd(&gstats[gi+1], g2);
  }
  // coords + zero pad (chunk 28): wave 0, one record per lane
  if (t < 64) {
    int w = wt*64 + t;
    if (w < Ww) {
      u16* rc = xh + ((size_t)(b*HP + h+1)*WP + (w+1))*ICP1 + 896;
      u32 cw0 = (u32)f2bf((float)w*(2.f/359.f) - 1.f) | ((u32)f2bf((float)h*(2.f/119.f) - 1.f) << 16);
      ((uint4*)rc)[0] = make_uint4(cw0, 0, 0, 0);
      ((uint4*)rc)[1] = make_uint4(0,0,0,0);
      ((uint4*)rc)[2] = make_uint4(0,0,0,0);
      ((uint4*)rc)[3] = make_uint4(0,0,0,0);
    }
  }
}

// ---------- pass A: group-norm -> lr into lrs[ch 0..128), zeros 176..192), per-pixel norm ----------
__global__ __launch_bounds__(256) void k_passA(const u16* __restrict__ mh, const float* __restrict__ gg,
    const float* __restrict__ gb, const float* __restrict__ gstats, u16* __restrict__ lrs, float* __restrict__ cn)
{
  __shared__ float sg[128], sb[128], smu[32], srs[32];
  int tid = threadIdx.x;
  if (tid < 128){ sg[tid] = gg[tid]; sb[tid] = gb[tid]; }
  else if (tid < 160){
    int i = tid-128;
    float s = gstats[2*i], s2 = gstats[2*i+1];
    float mu = s * (1.f/345600.f);
    float var = s2 * (1.f/345600.f) - mu*mu; if (var < 0.f) var = 0.f;
    smu[i] = mu; srs[i] = rsqrtf(var + 1e-5f);
  }
  __syncthreads();
  int p = blockIdx.x*256 + tid; if (p >= PIX) return;
  int b = p / HW, pix = p - b*HW, h = pix/Ww, w = pix - h*Ww;
  const uint4* src = (const uint4*)(mh + (size_t)p*128);
  u16* dst = lrs + ((size_t)(b*HP + h+1)*WP + (w+1))*ICP2;
  float ss = 0.f;
  #pragma unroll
  for (int t = 0; t < 16; ++t) {
    uint4 v = src[t];
    u32 wds[4] = {v.x, v.y, v.z, v.w};
    u32 ot[4];
    #pragma unroll
    for (int e = 0; e < 4; ++e) {
      int c0 = t*8 + e*2;
      int g0 = b*16 + (c0>>3);
      float a0 = (bflo(wds[e]) - smu[g0])*srs[g0]*sg[c0]   + sb[c0];
      float a1 = (bfhi(wds[e]) - smu[g0])*srs[g0]*sg[c0+1] + sb[c0+1];
      ss += a0*a0 + a1*a1;
      ot[e] = (u32)f2bf(a0) | ((u32)f2bf(a1) << 16);
    }
    ((uint4*)dst)[t] = make_uint4(ot[0], ot[1], ot[2], ot[3]);
  }
  uint4 z = make_uint4(0,0,0,0);
  ((uint4*)dst)[22] = z; ((uint4*)dst)[23] = z;      // channels 176..191
  cn[p] = fmaxf(sqrtf(ss), 1e-8f);
}

// ---------- pass B: 48 dilated cosine sims into lrs[ch 128..176) ----------
__global__ __launch_bounds__(256) void k_passB(u16* __restrict__ lrs, const float* __restrict__ cn)
{
  int p = blockIdx.x*256 + threadIdx.x; if (p >= PIX) return;
  int b = p / HW, pix = p - b*HW, h = pix/Ww, w = pix - h*Ww;
  u16* base = lrs + ((size_t)(b*HP + h+1)*WP + (w+1))*ICP2;
  uint4 own[16];
  #pragma unroll
  for (int t = 0; t < 16; ++t) own[t] = ((const uint4*)base)[t];
  float cnp = cn[p];
  u32 outw[24] __attribute__((aligned(16)));
  int k = 0;
  for (int i = 0; i < 7; ++i)
    for (int j = 0; j < 7; ++j) {
      if (i == 3 && j == 3) continue;
      int hq = h + 2*i - 6, wq = w + 2*j - 6;
      float sim = 0.f;
      if ((unsigned)hq < 120u && (unsigned)wq < 360u) {
        const u16* nb = lrs + ((size_t)(b*HP + hq+1)*WP + (wq+1))*ICP2;
        float dot = 0.f;
        #pragma unroll
        for (int t = 0; t < 16; ++t) {
          uint4 a = own[t]; uint4 c = ((const uint4*)nb)[t];
          dot += bflo(a.x)*bflo(c.x) + bfhi(a.x)*bfhi(c.x);
          dot += bflo(a.y)*bflo(c.y) + bfhi(a.y)*bfhi(c.y);
          dot += bflo(a.z)*bflo(c.z) + bfhi(a.z)*bfhi(c.z);
          dot += bflo(a.w)*bflo(c.w) + bfhi(a.w)*bfhi(c.w);
        }
        sim = dot / (cnp * cn[b*HW + hq*Ww + wq]);
      }
      u32 bv = f2bf(sim);
      if (k & 1) outw[k>>1] |= bv << 16; else outw[k>>1] = bv;
      ++k;
    }
  #pragma unroll
  for (int t = 0; t < 6; ++t) ((uint4*)(base + 128))[t] = ((uint4*)outw)[t];
}

// ---------- implicit-GEMM 3x3 conv, bf16 MFMA 16x16x32, BK=64 staging ----------
// v6 = v4 (64w tile, best measured anchor) + depth-3 B-ring with cross-barrier
// wraparound. 18 % 3 == 0 keeps the b0/b1/b2 ring phase-aligned across C-iters:
// subtiles 15..17 of iter C prefetch subtiles 0..2 of iter C+1, so those loads
// stay in flight across the __syncthreads (FIFO drain waits, doesn't reissue).
// Prefetch distance = 3 subtiles (~240-360cy of MFMA+addr issue) >= L2 latency,
// vs v4's distance-1 (~80-160cy) which left per-subtile stalls (Mfma 25%).
// v5 lesson: occupancy 2x (38%) made it WORSE (429us) -- latency is per-wave,
// fix the prefetch distance, not TLP.
template<int NSUPER, int NCTOT, int ICPAD, int OC, int NWM, int NWN, bool RELU, bool OUTF32>
__global__ __launch_bounds__(256, 2) void k_conv(const u16* __restrict__ inb, const u16* __restrict__ wf,
                                                 const float* __restrict__ bias, void* __restrict__ outp)
{
  static_assert(NWM*NWN == 4, "4 waves");
  constexpr int WM = 8/NWM;
  constexpr int WN = (OC/16)/NWN;
  __shared__ __align__(16) u16 alds0[4*66*64];     // 33,792 B each
  __shared__ __align__(16) u16 alds1[4*66*64];
  const int wt = blockIdx.x, h2 = blockIdx.y, b = blockIdx.z;
  const int h0 = h2*2, w0 = wt*64;
  const int tid = threadIdx.x, wid = tid >> 6, lane = tid & 63;
  const int q = lane >> 4, n = lane & 15;
  const int mi = wid / NWN, ni = wid % NWN;

  f32x4 zz = {0.f,0.f,0.f,0.f};
  f32x4 acc[WM][WN];
  #pragma unroll
  for (int a = 0; a < WM; ++a)
    #pragma unroll
    for (int bq = 0; bq < WN; ++bq) acc[a][bq] = zz;

  bf16x8 b0[WN], b1[WN], b2[WN];           // depth-3 B prefetch ring (named)

  const size_t pixbase = (size_t)(b*HP + h0)*WP + w0;
  const u16* wbase = wf + ((size_t)(ni*WN)*16 + n)*32 + q*8;   // oc-gn stride 16*32

  // wave `wid` stages input row wid: 66 wc x 8 units of 16B, XOR-swizzled
  // (pre-swizzled GLOBAL source, linear LDS dest -- gl_lds requirement)
  auto STAGE = [&](u16* dst, int C){
    const int row = wid;
    const u16* gbase = inb + (pixbase + (size_t)row*WP)*ICPAD + C*64;
    #pragma unroll
    for (int o = 0; o < 9; ++o) {
      if (o < 8 || lane < 16) {
        int f = o*64 + lane;                  // 0..527
        int wc = f >> 3, us = f & 7;
        int ridx = row*66 + wc;
        int usrc = us ^ (ridx & 7);
        gl_lds16(gbase + (size_t)wc*ICPAD + usrc*8, dst + (row*528 + o*64)*8);
      }
    }
  };

  // load B set for flat subtile f = s*9+tap of superchunk C into bb[]
  auto LOADB = [&](bf16x8 (&bb)[WN], int C, int f){
    const int s = f/9, tap = f%9;
    #pragma unroll
    for (int gn = 0; gn < WN; ++gn)
      bb[gn] = *(const bf16x8*)(wbase + (((size_t)tap*NCTOT + C*2+s)*OC + gn*16)*32);
  };

  // compute flat subtile f with B fragments bb[]
  auto CSUB = [&](const u16* buf, int f, const bf16x8 (&bb)[WN]){
    const int s = f/9, tap = f%9;
    const int kh = tap/3, kw = tap%3;
    bf16x8 afr[WM];
    #pragma unroll
    for (int gm = 0; gm < WM; ++gm) {
      int G = mi*WM + gm;
      int idx = ((G>>2) + kh)*66 + (G&3)*16 + n + kw;
      int us = (s*4 + q) ^ (idx & 7);
      afr[gm] = *(const bf16x8*)(buf + (idx*8 + us)*8);
    }
    #pragma unroll
    for (int gm = 0; gm < WM; ++gm)
      #pragma unroll
      for (int gn = 0; gn < WN; ++gn)
        acc[gm][gn] = __builtin_amdgcn_mfma_f32_16x16x32_bf16(afr[gm], bb[gn], acc[gm][gn], 0, 0, 0);
  };

  // PHASE(C): stage next A-tile, then 18 subtiles; each subtile f computes
  // with ring slot f%3 and refills that slot with subtile f+3 (wrapping into
  // C+1 for f>=15, so those loads cross the barrier in flight).
  auto PHASE = [&](const u16* cur, u16* nxt, int C){
    if (C + 1 < NSUPER) STAGE(nxt, C + 1);
    #pragma unroll
    for (int f = 0; f < 18; ++f) {
      const int fn = f + 3;
      if ((f % 3) == 0) {
        CSUB(cur, f, b0);
        if (fn < 18) LOADB(b0, C, fn); else if (C + 1 < NSUPER) LOADB(b0, C + 1, fn - 18);
      } else if ((f % 3) == 1) {
        CSUB(cur, f, b1);
        if (fn < 18) LOADB(b1, C, fn); else if (C + 1 < NSUPER) LOADB(b1, C + 1, fn - 18);
      } else {
        CSUB(cur, f, b2);
        if (fn < 18) LOADB(b2, C, fn); else if (C + 1 < NSUPER) LOADB(b2, C + 1, fn - 18);
      }
    }
    __syncthreads();
  };

  LOADB(b0, 0, 0);                         // prime the ring
  LOADB(b1, 0, 1);
  LOADB(b2, 0, 2);
  STAGE(alds0, 0);
  __syncthreads();
  for (int CC = 0; CC < NSUPER; CC += 2) {
    PHASE(alds0, alds1, CC);
    if (CC + 1 < NSUPER) PHASE(alds1, alds0, CC + 1);
  }

  #pragma unroll
  for (int gn = 0; gn < WN; ++gn) {
    int oc = (ni*WN + gn)*16 + n;
    float bv = bias[oc];
    #pragma unroll
    for (int gm = 0; gm < WM; ++gm) {
      int G = mi*WM + gm;
      #pragma unroll
      for (int r = 0; r < 4; ++r) {
        int p = G*16 + q*4 + r;
        int w = w0 + (p & 63);
        if (w < Ww) {
          int h = h0 + (p >> 6);
          float v = acc[gm][gn][r] + bv;
          if (RELU) v = fmaxf(v, 0.f);
          size_t oi = ((size_t)(b*Hh + h)*Ww + w)*OC + oc;
          if (OUTF32) ((float*)outp)[oi] = v;
          else        ((u16*)outp)[oi]  = f2bf(v);
        }
      }
    }
  }
}

// ---------- deform-sample 3 offset sets + average, NCHW f32 out ----------
__device__ __forceinline__ void samp_add(float* acc, const u16* __restrict__ feat,
                                         int b, int h, int w, float ox, float oy, int c0)
{
  float ix = (float)w + ox, iy = (float)h + oy;
  float x0f = floorf(ix), y0f = floorf(iy);
  float wx = ix - x0f, wy = iy - y0f;
  int x0 = (int)x0f, y0 = (int)y0f;
  int x0c = min(max(x0, 0), 359),   x1c = min(max(x0+1, 0), 359);
  int y0c = min(max(y0, 0), 119),   y1c = min(max(y0+1, 0), 119);
  const u16* fb = feat + (size_t)b*HW*128 + c0;
  uint4 v00 = *(const uint4*)(fb + ((size_t)y0c*Ww + x0c)*128);
  uint4 v01 = *(const uint4*)(fb + ((size_t)y0c*Ww + x1c)*128);
  uint4 v10 = *(const uint4*)(fb + ((size_t)y1c*Ww + x0c)*128);
  uint4 v11 = *(const uint4*)(fb + ((size_t)y1c*Ww + x1c)*128);
  float w00 = (1.f-wx)*(1.f-wy), w01 = wx*(1.f-wy), w10 = (1.f-wx)*wy, w11 = wx*wy;
  u32 a00[4] = {v00.x,v00.y,v00.z,v00.w};
  u32 a01[4] = {v01.x,v01.y,v01.z,v01.w};
  u32 a10[4] = {v10.x,v10.y,v10.z,v10.w};
  u32 a11[4] = {v11.x,v11.y,v11.z,v11.w};
  #pragma unroll
  for (int e = 0; e < 4; ++e) {
    acc[2*e]   += w00*bflo(a00[e]) + w01*bflo(a01[e]) + w10*bflo(a10[e]) + w11*bflo(a11[e]);
    acc[2*e+1] += w00*bfhi(a00[e]) + w01*bfhi(a01[e]) + w10*bfhi(a10[e]) + w11*bfhi(a11[e]);
  }
}

__global__ __launch_bounds__(256) void k_sample(const u16* __restrict__ feat, const float* __restrict__ offs,
                                                float* __restrict__ out)
{
  int lane = threadIdx.x & 63;
  int cc = blockIdx.y*4 + (threadIdx.x >> 6);     // 0..15: 8-channel chunk
  int pix = blockIdx.x*64 + lane;                 // 675*64 = 43200 exact
  int b = blockIdx.z;
  int h = pix/Ww, w = pix - h*Ww;
  const float* ob = offs + ((size_t)b*HW + pix)*64;
  float acc[8] = {0,0,0,0,0,0,0,0};
  samp_add(acc, feat, b, h, w, ob[cc],          ob[16+cc],       cc*8);   // off0: 16 groups
  samp_add(acc, feat, b, h, w, ob[32+(cc>>1)],  ob[40+(cc>>1)],  cc*8);   // off1: 8 groups
  samp_add(acc, feat, b, h, w, ob[48+(cc>>2)],  ob[52+(cc>>2)],  cc*8);   // off2: 4 groups
  #pragma unroll
  for (int e = 0; e < 8; ++e)
    out[((size_t)(b*128 + cc*8 + e))*HW + pix] = acc[e] * (1.f/3.f);
}

// ---------- launch ----------
extern "C" void kernel_launch(void* const* d_in, const int* in_sizes, int n_in,
                              void* d_out, int out_size, void* d_ws, size_t ws_size,
                              hipStream_t stream)
{
  (void)in_sizes; (void)n_in; (void)out_size; (void)ws_size;
  const float* x      = (const float*)d_in[0];
  const float* conv_w = (const float*)d_in[1];
  const float* conv_b = (const float*)d_in[2];
  const float* gn_g   = (const float*)d_in[3];
  const float* gn_b   = (const float*)d_in[4];
  const float* off_w  = (const float*)d_in[5];
  const float* off_b  = (const float*)d_in[6];
  const float* off1_w = (const float*)d_in[7];
  const float* off1_b = (const float*)d_in[8];
  const float* off2_w = (const float*)d_in[9];
  const float* off2_b = (const float*)d_in[10];
  float* out = (float*)d_out;

  char* ws = (char*)d_ws;
  u16*   xh   = (u16*)(ws + OFF_XH);
  u16*   lrs  = (u16*)(ws + OFF_LRS);
  u16*   mh   = (u16*)(ws + OFF_FEAT);   // aliases feat (mh consumed in passA before conv writes feat)
  u16*   feat = mh;
  float* offs = (float*)(ws + OFF_XH);   // aliases xh (xh consumed by conv1 before conv2 writes offs)
  u16*   w1f  = (u16*)(ws + OFF_W1F);
  u16*   w2f  = (u16*)(ws + OFF_W2F);
  float* w2b  = (float*)(ws + OFF_W2B);
  float* cn   = (float*)(ws + OFF_CN);
  float* gst  = (float*)(ws + OFF_GST);

  k_init    <<<dim3(1055),      dim3(256), 0, stream>>>(xh, lrs, gst);
  k_prep_w1 <<<dim3(4320),      dim3(256), 0, stream>>>(conv_w, w1f);
  k_prep_w2 <<<dim3(432),       dim3(256), 0, stream>>>(off_w, off1_w, off2_w, off_b, off1_b, off2_b, w2f, w2b);
  k_packmean<<<dim3(6,120,2),   dim3(256), 0, stream>>>(x, xh, mh, gst);
  k_passA   <<<dim3(338),       dim3(256), 0, stream>>>(mh, gn_g, gn_b, gst, lrs, cn);
  k_passB   <<<dim3(338),       dim3(256), 0, stream>>>(lrs, cn);
  k_conv<15,30,ICP1,128,2,2,true ,false><<<dim3(6,60,2), dim3(256), 0, stream>>>(xh,  w1f, conv_b, feat);
  k_conv< 3, 6,ICP2, 64,4,1,false,true ><<<dim3(6,60,2), dim3(256), 0, stream>>>(lrs, w2f, w2b,   offs);
  k_sample  <<<dim3(675,4,2),   dim3(256), 0, stream>>>(feat, offs, out);
}

// Round 8
// 1224.350 us; speedup vs baseline: 1.0619x; 1.0014x over previous
//
#include <hip/hip_runtime.h>

typedef unsigned short u16;
typedef unsigned int   u32;
typedef short bf16x8 __attribute__((ext_vector_type(8)));
typedef float f32x4  __attribute__((ext_vector_type(4)));

// ---------- geometry ----------
#define Bn   2
#define Nn   7
#define Cc   128
#define Hh   120
#define Ww   360
#define HW   43200          // Hh*Ww
#define PIX  86400          // Bn*HW
#define HP   122            // padded H (h index +1)
#define WP   362            // padded W (w index +1)
#define ICP1 928            // 29*32 (898 real + pad)
#define ICP2 192            // 6*32  (176 real + pad)

// ---------- ws layout (bytes, 256-aligned) ----------
constexpr size_t AL(size_t x){ return (x + 255) & ~size_t(255); }
constexpr size_t XH_BYTES  = (size_t)Bn*HP*WP*ICP1*2;      // ~163.9 MB
constexpr size_t LRS_BYTES = (size_t)Bn*HP*WP*ICP2*2;      // ~33.9 MB
constexpr size_t OFF_XH  = 0;
constexpr size_t OFF_LRS = AL(OFF_XH + XH_BYTES + 65536);     // slack for conv A-tile overrun
constexpr size_t OFF_FEAT= AL(OFF_LRS + LRS_BYTES + 65536);   // feat aliases mh (mh dead before conv)
constexpr size_t OFF_W1F = AL(OFF_FEAT + (size_t)PIX*128*2);
constexpr size_t OFF_W2F = AL(OFF_W1F + (size_t)9*30*128*32*2);   // 30 chunks (29 real + zero pad)
constexpr size_t OFF_W2B = AL(OFF_W2F + (size_t)9*6*64*32*2);
constexpr size_t OFF_CN  = AL(OFF_W2B + 256);
constexpr size_t OFF_GST = AL(OFF_CN + (size_t)PIX*4);
// offsets buffer (f32, PIX*64*4 = 22.1MB) aliases xh (xh dead after main conv)

// ---------- helpers ----------
__device__ __forceinline__ float bf2f(u16 h){ union{u32 u; float f;} c; c.u = ((u32)h)<<16; return c.f; }
__device__ __forceinline__ u16 f2bf(float f){
  union{float f; u32 u;} c; c.f = f;
  u32 r = (c.u + 0x7FFFu + ((c.u>>16)&1u)) >> 16;
  return (u16)r;
}
__device__ __forceinline__ float bflo(u32 a){ union{u32 u; float f;} c; c.u = a<<16;          return c.f; }
__device__ __forceinline__ float bfhi(u32 a){ union{u32 u; float f;} c; c.u = a & 0xffff0000u; return c.f; }

__device__ __forceinline__ void gl_lds16(const u16* g, u16* l){
  __builtin_amdgcn_global_load_lds((const __attribute__((address_space(1))) void*)g,
                                   (__attribute__((address_space(3))) void*)l, 16, 0, 0);
}

// ---------- init: zero gstats + spatial pads of xh / lrs ----------
__global__ __launch_bounds__(256) void k_init(u16* __restrict__ xh, u16* __restrict__ lrs, float* __restrict__ gstats)
{
  int t = blockIdx.x*256 + threadIdx.x;
  if (t < 64) gstats[t] = 0.f;
  t -= 64;
  if (t < 0 || t >= 2*964*140) return;
  int b = t / (964*140); int r = t - b*(964*140);
  int i = r / 140, chunk = r - i*140;
  int hp, wp;
  if (i < 362)      { hp = 0;   wp = i; }
  else if (i < 724) { hp = 121; wp = i-362; }
  else { int j = i-724; hp = 1 + (j>>1); wp = (j&1) ? 361 : 0; }
  size_t pixel = (size_t)(b*HP + hp)*WP + wp;
  uint4 z = make_uint4(0,0,0,0);
  if (chunk < 116) ((uint4*)(xh  + pixel*ICP1))[chunk]      = z;
  else             ((uint4*)(lrs + pixel*ICP2))[chunk-116]  = z;
}

// ---------- weight prep: MFMA-fragment-ordered  [tap][chunk(30)][oc][32] ----------
__global__ __launch_bounds__(256) void k_prep_w1(const float* __restrict__ cw, u16* __restrict__ w1f)
{
  int t = blockIdx.x*256 + threadIdx.x;      // 9*30*128*32
  int kk = t & 31; int rest = t >> 5;
  int oc = rest & 127; rest >>= 7;           // rest = tap*30 + c
  int c = rest % 30, tap = rest / 30;
  int ic = c*32 + kk;
  u16 v = 0;
  if (ic < 898) v = f2bf(cw[(size_t)oc*8082 + (size_t)ic*9 + tap]);
  w1f[t] = v;
}

__global__ __launch_bounds__(256) void k_prep_w2(const float* __restrict__ ow0, const float* __restrict__ ow1,
    const float* __restrict__ ow2, const float* __restrict__ ob0, const float* __restrict__ ob1,
    const float* __restrict__ ob2, u16* __restrict__ w2f, float* __restrict__ w2b)
{
  int t = blockIdx.x*256 + threadIdx.x;      // 9*6*64*32
  if (t < 64) {
    float bv = 0.f;
    if (t < 32)      bv = ob0[t];
    else if (t < 48) bv = ob1[t-32];
    else if (t < 56) bv = ob2[t-48];
    w2b[t] = bv;
  }
  int kk = t & 31; int rest = t >> 5;
  int oc = rest & 63; rest >>= 6;            // rest = tap*6 + c
  int c = rest % 6, tap = rest / 6;
  int ic = c*32 + kk;
  u16 v = 0;
  if (ic < 176) {
    if (oc < 32)      v = f2bf(ow0[(size_t)oc*1584      + (size_t)ic*9 + tap]);
    else if (oc < 48) v = f2bf(ow1[(size_t)(oc-32)*1584 + (size_t)ic*9 + tap]);
    else if (oc < 56) v = f2bf(ow2[(size_t)(oc-48)*1584 + (size_t)ic*9 + tap]);
  }
  w2f[t] = v;
}

// ---------- fused pack + mean + GN stats, v3 ----------
// v3: xh/mh stores routed through a 16KB LDS transpose so each wave writes
// full-line 256B segments. v2's direct stores were 16B/lane at 7424B stride
// (one 16B chunk per 64B line -> 2-4x HBM write amplification on 158MB).
// Swizzle chunk ^ (px>>2): pack-phase lanes (px stride 4) and store-phase
// lanes (ch 0..15 at fixed px) both land 2-way-or-free on LDS banks.
__global__ __launch_bounds__(256) void k_packmean(const float* __restrict__ x, u16* __restrict__ xh,
                                                  u16* __restrict__ mh, float* __restrict__ gstats)
{
  __shared__ __align__(16) uint4 sbuf[64*16];     // 16 KB: [px][chunk] swizzled
  int wt = blockIdx.x, h = blockIdx.y, b = blockIdx.z;
  int t = threadIdx.x;
  int wg = t & 15, cq = t >> 4;
  int w0 = wt*64 + wg*4;
  bool ok = (w0 < Ww);                 // 4-pixel group all-valid or all-invalid
  int w0c = ok ? w0 : 0;
  const float* xb = x + (size_t)b*7*128*HW + (size_t)h*Ww + w0c;
  const size_t rowbase = (size_t)(b*HP + h+1)*WP;

  float msum[8][4];
  #pragma unroll
  for (int c = 0; c < 8; ++c)
    #pragma unroll
    for (int s = 0; s < 4; ++s) msum[c][s] = 0.f;

  #pragma unroll
  for (int nn = 0; nn < 7; ++nn) {
    float4 v[8];
    const float* src = xb + (size_t)(nn*128 + cq*8)*HW;
    #pragma unroll
    for (int c = 0; c < 8; ++c)
      v[c] = ok ? *(const float4*)(src + (size_t)c*HW) : make_float4(0.f,0.f,0.f,0.f);
    #pragma unroll
    for (int c = 0; c < 8; ++c) {
      const float* vf = (const float*)&v[c];
      #pragma unroll
      for (int s = 0; s < 4; ++s) msum[c][s] += vf[s];
    }
    // pack into LDS transpose buffer
    #pragma unroll
    for (int s = 0; s < 4; ++s) {
      u32 ow[4];
      #pragma unroll
      for (int e = 0; e < 4; ++e) {
        const float* lo = (const float*)&v[2*e];
        const float* hi = (const float*)&v[2*e+1];
        ow[e] = (u32)f2bf(lo[s]) | ((u32)f2bf(hi[s]) << 16);
      }
      int px = wg*4 + s;
      sbuf[px*16 + (cq ^ (px>>2))] = make_uint4(ow[0],ow[1],ow[2],ow[3]);
    }
    __syncthreads();
    // linear store: 64 px x 16 chunks; wave covers 4 records x 256B full lines
    #pragma unroll
    for (int step = 0; step < 4; ++step) {
      int tt = step*256 + t;
      int px = tt >> 4, ch = tt & 15;
      int w = wt*64 + px;
      if (w < Ww) {
        uint4 val = sbuf[px*16 + (ch ^ (px>>2))];
        *(uint4*)(xh + (rowbase + (w+1))*ICP1 + nn*128 + ch*8) = val;
      }
    }
    __syncthreads();
  }
  // mean -> mh (same LDS transpose), GN partials
  float g1 = 0.f, g2 = 0.f;
  #pragma unroll
  for (int c = 0; c < 8; ++c)
    #pragma unroll
    for (int s = 0; s < 4; ++s) {
      float m = msum[c][s] * (1.f/7.f);
      msum[c][s] = m;
      g1 += m; g2 += m*m;
    }
  #pragma unroll
  for (int s = 0; s < 4; ++s) {
    u32 ow[4];
    #pragma unroll
    for (int e = 0; e < 4; ++e)
      ow[e] = (u32)f2bf(msum[2*e][s]) | ((u32)f2bf(msum[2*e+1][s]) << 16);
    int px = wg*4 + s;
    sbuf[px*16 + (cq ^ (px>>2))] = make_uint4(ow[0],ow[1],ow[2],ow[3]);
  }
  __syncthreads();
  #pragma unroll
  for (int step = 0; step < 4; ++step) {
    int tt = step*256 + t;
    int px = tt >> 4, ch = tt & 15;
    int w = wt*64 + px;
    if (w < Ww)
      *(uint4*)(mh + ((size_t)b*HW + (size_t)h*Ww + w)*128 + ch*8) = sbuf[px*16 + (ch ^ (px>>2))];
  }
  // GN stats reduce (within 16-lane wg groups)
  #pragma unroll
  for (int o = 8; o > 0; o >>= 1) { g1 += __shfl_down(g1, o, 16); g2 += __shfl_down(g2, o, 16); }
  if (wg == 0 && ok) {
    int gi = (b*16 + cq)*2;
    atomicAdd(&gstats[gi],   g1);
    atomicAdd(&gstats[gi+1], g2);
  } else if (wg == 0 && !ok) {           // zero-contribution still must not add garbage
    // (msum is all zeros when !ok, so g1==g2==0; atomics skipped safely)
  }
  // coords + zero pad (chunk 28): wave 0, one record per lane (64B/line, full)
  if (t < 64) {
    int w = wt*64 + t;
    if (w < Ww) {
      u16* rc = xh + (rowbase + (w+1))*ICP1 + 896;
      u32 cw0 = (u32)f2bf((float)w*(2.f/359.f) - 1.f) | ((u32)f2bf((float)h*(2.f/119.f) - 1.f) << 16);
      ((uint4*)rc)[0] = make_uint4(cw0, 0, 0, 0);
      ((uint4*)rc)[1] = make_uint4(0,0,0,0);
      ((uint4*)rc)[2] = make_uint4(0,0,0,0);
      ((uint4*)rc)[3] = make_uint4(0,0,0,0);
    }
  }
}

// ---------- pass A v2: 16 threads per pixel -> contiguous 256B reads/writes ----------
__global__ __launch_bounds__(256) void k_passA(const u16* __restrict__ mh, const float* __restrict__ gg,
    const float* __restrict__ gb, const float* __restrict__ gstats, u16* __restrict__ lrs, float* __restrict__ cn)
{
  __shared__ float sg[128], sb[128], smu[32], srs[32];
  int tid = threadIdx.x;
  if (tid < 128){ sg[tid] = gg[tid]; sb[tid] = gb[tid]; }
  else if (tid < 160){
    int i = tid-128;
    float s = gstats[2*i], s2 = gstats[2*i+1];
    float mu = s * (1.f/345600.f);
    float var = s2 * (1.f/345600.f) - mu*mu; if (var < 0.f) var = 0.f;
    smu[i] = mu; srs[i] = rsqrtf(var + 1e-5f);
  }
  __syncthreads();
  int ch = tid & 15;                         // chunk (8 channels) within record
  int p = blockIdx.x*16 + (tid >> 4);        // 5400*16 = 86400 exact
  int b = p / HW, pix = p - b*HW, h = pix/Ww, w = pix - h*Ww;
  uint4 v = ((const uint4*)(mh + (size_t)p*128))[ch];
  u16* dst = lrs + ((size_t)(b*HP + h+1)*WP + (w+1))*ICP2;
  u32 wds[4] = {v.x, v.y, v.z, v.w};
  u32 ot[4];
  float ss = 0.f;
  int g0 = b*16 + ch;
  float mu = smu[g0], rs = srs[g0];
  #pragma unroll
  for (int e = 0; e < 4; ++e) {
    int c0 = ch*8 + e*2;
    float a0 = (bflo(wds[e]) - mu)*rs*sg[c0]   + sb[c0];
    float a1 = (bfhi(wds[e]) - mu)*rs*sg[c0+1] + sb[c0+1];
    ss += a0*a0 + a1*a1;
    ot[e] = (u32)f2bf(a0) | ((u32)f2bf(a1) << 16);
  }
  ((uint4*)dst)[ch] = make_uint4(ot[0], ot[1], ot[2], ot[3]);
  uint4 z = make_uint4(0,0,0,0);
  if (ch == 14) ((uint4*)dst)[22] = z;       // channels 176..183
  if (ch == 15) ((uint4*)dst)[23] = z;       // channels 184..191
  #pragma unroll
  for (int o = 8; o > 0; o >>= 1) ss += __shfl_down(ss, o, 16);
  if (ch == 0) cn[p] = fmaxf(sqrtf(ss), 1e-8f);
}

// ---------- pass B: 48 dilated cosine sims into lrs[ch 128..176) ----------
__global__ __launch_bounds__(256) void k_passB(u16* __restrict__ lrs, const float* __restrict__ cn)
{
  int p = blockIdx.x*256 + threadIdx.x; if (p >= PIX) return;
  int b = p / HW, pix = p - b*HW, h = pix/Ww, w = pix - h*Ww;
  u16* base = lrs + ((size_t)(b*HP + h+1)*WP + (w+1))*ICP2;
  uint4 own[16];
  #pragma unroll
  for (int t = 0; t < 16; ++t) own[t] = ((const uint4*)base)[t];
  float cnp = cn[p];
  u32 outw[24] __attribute__((aligned(16)));
  int k = 0;
  for (int i = 0; i < 7; ++i)
    for (int j = 0; j < 7; ++j) {
      if (i == 3 && j == 3) continue;
      int hq = h + 2*i - 6, wq = w + 2*j - 6;
      float sim = 0.f;
      if ((unsigned)hq < 120u && (unsigned)wq < 360u) {
        const u16* nb = lrs + ((size_t)(b*HP + hq+1)*WP + (wq+1))*ICP2;
        float dot = 0.f;
        #pragma unroll
        for (int t = 0; t < 16; ++t) {
          uint4 a = own[t]; uint4 c = ((const uint4*)nb)[t];
          dot += bflo(a.x)*bflo(c.x) + bfhi(a.x)*bfhi(c.x);
          dot += bflo(a.y)*bflo(c.y) + bfhi(a.y)*bfhi(c.y);
          dot += bflo(a.z)*bflo(c.z) + bfhi(a.z)*bfhi(c.z);
          dot += bflo(a.w)*bflo(c.w) + bfhi(a.w)*bfhi(c.w);
        }
        sim = dot / (cnp * cn[b*HW + hq*Ww + wq]);
      }
      u32 bv = f2bf(sim);
      if (k & 1) outw[k>>1] |= bv << 16; else outw[k>>1] = bv;
      ++k;
    }
  #pragma unroll
  for (int t = 0; t < 6; ++t) ((uint4*)(base + 128))[t] = ((uint4*)outw)[t];
}

// ---------- implicit-GEMM 3x3 conv, bf16 MFMA 16x16x32, BK=64 staging ----------
// v6 (unchanged, best measured 333us): 64w tile + depth-3 B-ring with
// cross-barrier wraparound. See round-7 notes.
template<int NSUPER, int NCTOT, int ICPAD, int OC, int NWM, int NWN, bool RELU, bool OUTF32>
__global__ __launch_bounds__(256, 2) void k_conv(const u16* __restrict__ inb, const u16* __restrict__ wf,
                                                 const float* __restrict__ bias, void* __restrict__ outp)
{
  static_assert(NWM*NWN == 4, "4 waves");
  constexpr int WM = 8/NWM;
  constexpr int WN = (OC/16)/NWN;
  __shared__ __align__(16) u16 alds0[4*66*64];     // 33,792 B each
  __shared__ __align__(16) u16 alds1[4*66*64];
  const int wt = blockIdx.x, h2 = blockIdx.y, b = blockIdx.z;
  const int h0 = h2*2, w0 = wt*64;
  const int tid = threadIdx.x, wid = tid >> 6, lane = tid & 63;
  const int q = lane >> 4, n = lane & 15;
  const int mi = wid / NWN, ni = wid % NWN;

  f32x4 zz = {0.f,0.f,0.f,0.f};
  f32x4 acc[WM][WN];
  #pragma unroll
  for (int a = 0; a < WM; ++a)
    #pragma unroll
    for (int bq = 0; bq < WN; ++bq) acc[a][bq] = zz;

  bf16x8 b0[WN], b1[WN], b2[WN];           // depth-3 B prefetch ring (named)

  const size_t pixbase = (size_t)(b*HP + h0)*WP + w0;
  const u16* wbase = wf + ((size_t)(ni*WN)*16 + n)*32 + q*8;   // oc-gn stride 16*32

  auto STAGE = [&](u16* dst, int C){
    const int row = wid;
    const u16* gbase = inb + (pixbase + (size_t)row*WP)*ICPAD + C*64;
    #pragma unroll
    for (int o = 0; o < 9; ++o) {
      if (o < 8 || lane < 16) {
        int f = o*64 + lane;                  // 0..527
        int wc = f >> 3, us = f & 7;
        int ridx = row*66 + wc;
        int usrc = us ^ (ridx & 7);
        gl_lds16(gbase + (size_t)wc*ICPAD + usrc*8, dst + (row*528 + o*64)*8);
      }
    }
  };

  auto LOADB = [&](bf16x8 (&bb)[WN], int C, int f){
    const int s = f/9, tap = f%9;
    #pragma unroll
    for (int gn = 0; gn < WN; ++gn)
      bb[gn] = *(const bf16x8*)(wbase + (((size_t)tap*NCTOT + C*2+s)*OC + gn*16)*32);
  };

  auto CSUB = [&](const u16* buf, int f, const bf16x8 (&bb)[WN]){
    const int s = f/9, tap = f%9;
    const int kh = tap/3, kw = tap%3;
    bf16x8 afr[WM];
    #pragma unroll
    for (int gm = 0; gm < WM; ++gm) {
      int G = mi*WM + gm;
      int idx = ((G>>2) + kh)*66 + (G&3)*16 + n + kw;
      int us = (s*4 + q) ^ (idx & 7);
      afr[gm] = *(const bf16x8*)(buf + (idx*8 + us)*8);
    }
    #pragma unroll
    for (int gm = 0; gm < WM; ++gm)
      #pragma unroll
      for (int gn = 0; gn < WN; ++gn)
        acc[gm][gn] = __builtin_amdgcn_mfma_f32_16x16x32_bf16(afr[gm], bb[gn], acc[gm][gn], 0, 0, 0);
  };

  auto PHASE = [&](const u16* cur, u16* nxt, int C){
    if (C + 1 < NSUPER) STAGE(nxt, C + 1);
    #pragma unroll
    for (int f = 0; f < 18; ++f) {
      const int fn = f + 3;
      if ((f % 3) == 0) {
        CSUB(cur, f, b0);
        if (fn < 18) LOADB(b0, C, fn); else if (C + 1 < NSUPER) LOADB(b0, C + 1, fn - 18);
      } else if ((f % 3) == 1) {
        CSUB(cur, f, b1);
        if (fn < 18) LOADB(b1, C, fn); else if (C + 1 < NSUPER) LOADB(b1, C + 1, fn - 18);
      } else {
        CSUB(cur, f, b2);
        if (fn < 18) LOADB(b2, C, fn); else if (C + 1 < NSUPER) LOADB(b2, C + 1, fn - 18);
      }
    }
    __syncthreads();
  };

  LOADB(b0, 0, 0);                         // prime the ring
  LOADB(b1, 0, 1);
  LOADB(b2, 0, 2);
  STAGE(alds0, 0);
  __syncthreads();
  for (int CC = 0; CC < NSUPER; CC += 2) {
    PHASE(alds0, alds1, CC);
    if (CC + 1 < NSUPER) PHASE(alds1, alds0, CC + 1);
  }

  #pragma unroll
  for (int gn = 0; gn < WN; ++gn) {
    int oc = (ni*WN + gn)*16 + n;
    float bv = bias[oc];
    #pragma unroll
    for (int gm = 0; gm < WM; ++gm) {
      int G = mi*WM + gm;
      #pragma unroll
      for (int r = 0; r < 4; ++r) {
        int p = G*16 + q*4 + r;
        int w = w0 + (p & 63);
        if (w < Ww) {
          int h = h0 + (p >> 6);
          float v = acc[gm][gn][r] + bv;
          if (RELU) v = fmaxf(v, 0.f);
          size_t oi = ((size_t)(b*Hh + h)*Ww + w)*OC + oc;
          if (OUTF32) ((float*)outp)[oi] = v;
          else        ((u16*)outp)[oi]  = f2bf(v);
        }
      }
    }
  }
}

// ---------- deform-sample 3 offset sets + average, NCHW f32 out ----------
__device__ __forceinline__ void samp_add(float* acc, const u16* __restrict__ feat,
                                         int b, int h, int w, float ox, float oy, int c0)
{
  float ix = (float)w + ox, iy = (float)h + oy;
  float x0f = floorf(ix), y0f = floorf(iy);
  float wx = ix - x0f, wy = iy - y0f;
  int x0 = (int)x0f, y0 = (int)y0f;
  int x0c = min(max(x0, 0), 359),   x1c = min(max(x0+1, 0), 359);
  int y0c = min(max(y0, 0), 119),   y1c = min(max(y0+1, 0), 119);
  const u16* fb = feat + (size_t)b*HW*128 + c0;
  uint4 v00 = *(const uint4*)(fb + ((size_t)y0c*Ww + x0c)*128);
  uint4 v01 = *(const uint4*)(fb + ((size_t)y0c*Ww + x1c)*128);
  uint4 v10 = *(const uint4*)(fb + ((size_t)y1c*Ww + x0c)*128);
  uint4 v11 = *(const uint4*)(fb + ((size_t)y1c*Ww + x1c)*128);
  float w00 = (1.f-wx)*(1.f-wy), w01 = wx*(1.f-wy), w10 = (1.f-wx)*wy, w11 = wx*wy;
  u32 a00[4] = {v00.x,v00.y,v00.z,v00.w};
  u32 a01[4] = {v01.x,v01.y,v01.z,v01.w};
  u32 a10[4] = {v10.x,v10.y,v10.z,v10.w};
  u32 a11[4] = {v11.x,v11.y,v11.z,v11.w};
  #pragma unroll
  for (int e = 0; e < 4; ++e) {
    acc[2*e]   += w00*bflo(a00[e]) + w01*bflo(a01[e]) + w10*bflo(a10[e]) + w11*bflo(a11[e]);
    acc[2*e+1] += w00*bfhi(a00[e]) + w01*bfhi(a01[e]) + w10*bfhi(a10[e]) + w11*bfhi(a11[e]);
  }
}

__global__ __launch_bounds__(256) void k_sample(const u16* __restrict__ feat, const float* __restrict__ offs,
                                                float* __restrict__ out)
{
  int lane = threadIdx.x & 63;
  int cc = blockIdx.y*4 + (threadIdx.x >> 6);     // 0..15: 8-channel chunk
  int pix = blockIdx.x*64 + lane;                 // 675*64 = 43200 exact
  int b = blockIdx.z;
  int h = pix/Ww, w = pix - h*Ww;
  const float* ob = offs + ((size_t)b*HW + pix)*64;
  float acc[8] = {0,0,0,0,0,0,0,0};
  samp_add(acc, feat, b, h, w, ob[cc],          ob[16+cc],       cc*8);   // off0: 16 groups
  samp_add(acc, feat, b, h, w, ob[32+(cc>>1)],  ob[40+(cc>>1)],  cc*8);   // off1: 8 groups
  samp_add(acc, feat, b, h, w, ob[48+(cc>>2)],  ob[52+(cc>>2)],  cc*8);   // off2: 4 groups
  #pragma unroll
  for (int e = 0; e < 8; ++e)
    out[((size_t)(b*128 + cc*8 + e))*HW + pix] = acc[e] * (1.f/3.f);
}

// ---------- launch ----------
extern "C" void kernel_launch(void* const* d_in, const int* in_sizes, int n_in,
                              void* d_out, int out_size, void* d_ws, size_t ws_size,
                              hipStream_t stream)
{
  (void)in_sizes; (void)n_in; (void)out_size; (void)ws_size;
  const float* x      = (const float*)d_in[0];
  const float* conv_w = (const float*)d_in[1];
  const float* conv_b = (const float*)d_in[2];
  const float* gn_g   = (const float*)d_in[3];
  const float* gn_b   = (const float*)d_in[4];
  const float* off_w  = (const float*)d_in[5];
  const float* off_b  = (const float*)d_in[6];
  const float* off1_w = (const float*)d_in[7];
  const float* off1_b = (const float*)d_in[8];
  const float* off2_w = (const float*)d_in[9];
  const float* off2_b = (const float*)d_in[10];
  float* out = (float*)d_out;

  char* ws = (char*)d_ws;
  u16*   xh   = (u16*)(ws + OFF_XH);
  u16*   lrs  = (u16*)(ws + OFF_LRS);
  u16*   mh   = (u16*)(ws + OFF_FEAT);   // aliases feat (mh consumed in passA before conv writes feat)
  u16*   feat = mh;
  float* offs = (float*)(ws + OFF_XH);   // aliases xh (xh consumed by conv1 before conv2 writes offs)
  u16*   w1f  = (u16*)(ws + OFF_W1F);
  u16*   w2f  = (u16*)(ws + OFF_W2F);
  float* w2b  = (float*)(ws + OFF_W2B);
  float* cn   = (float*)(ws + OFF_CN);
  float* gst  = (float*)(ws + OFF_GST);

  k_init    <<<dim3(1055),      dim3(256), 0, stream>>>(xh, lrs, gst);
  k_prep_w1 <<<dim3(4320),      dim3(256), 0, stream>>>(conv_w, w1f);
  k_prep_w2 <<<dim3(432),       dim3(256), 0, stream>>>(off_w, off1_w, off2_w, off_b, off1_b, off2_b, w2f, w2b);
  k_packmean<<<dim3(6,120,2),   dim3(256), 0, stream>>>(x, xh, mh, gst);
  k_passA   <<<dim3(5400),      dim3(256), 0, stream>>>(mh, gn_g, gn_b, gst, lrs, cn);
  k_passB   <<<dim3(338),       dim3(256), 0, stream>>>(lrs, cn);
  k_conv<15,30,ICP1,128,2,2,true ,false><<<dim3(6,60,2), dim3(256), 0, stream>>>(xh,  w1f, conv_b, feat);
  k_conv< 3, 6,ICP2, 64,4,1,false,true ><<<dim3(6,60,2), dim3(256), 0, stream>>>(lrs, w2f, w2b,   offs);
  k_sample  <<<dim3(675,4,2),   dim3(256), 0, stream>>>(feat, offs, out);
}